// Round 6
// baseline (268.879 us; speedup 1.0000x reference)
//
#include <hip/hip_runtime.h>

// Blocks SNN forward: T=1024, TB=8, B=32, N=1024.
// R13: ILP-2 — each lane runs TWO independent chains.
//
// Evidence: R7 (reg prefetch), R9 (compiler waits), R11 (producer/consumer
// waves), R12 (4x coarser barriers) ALL converge on ~1600cy per block per
// chain with VALUBusy pinned at ~16%. The only model consistent with
// "every schedule identical" is per-wave serial-dependency latency: one
// chain per lane gives a wave zero ILP (serial f64 Horner + header chain +
// cross-block carry), occupancy is problem-capped at 1-2 waves/SIMD, so
// every dep-latency bubble and handshake latency is exposed and additive.
// Fix: interleave two independent chains per lane. Issue slots of one
// chain fill the stall bubbles of the other; all fixed per-iter costs
// (lgkm waits, barriers, producer latency) amortize over 2x work.
//
// Structure (carried from R12, proven absmax 0.0):
//   256 WGs x (1 consumer + 1 producer wave). WG owns chains
//   [wg0, wg0+128); lane l runs chains wg0+l and wg0+64+l.
//   Input tiles [8][128] f32 (4KB), RING=16 (64KB); sbuf 2x4 tiles (32KB).
//   LDS total 96KB -> exactly 1 WG/CU (perfect balance on 256 CUs).
//   G=4 blocks per barrier iter, NITER=32.
//   DMA layout: tile row-major [t][chain-wg0]; seg s (0..3) = rows 2s,2s+1,
//   lane p writes LDS bytes [1024s+16p,+16) = global
//   x[(b*8+2s+(p>>5))*BN + wg0 + (p&31)*4 ..+3]. Stores mirror it.
//   vmcnt (16-op DMA groups, 16-op drains, in-order counter):
//     prologue: groups 0,1 issued; vmcnt(16) = group 0 done.
//     j=0: dma g2, vmcnt(16) = group 1 done.
//     j=1..29: drain(j-1), dma(j+2), vmcnt(16) = group j+1 + stores done.
//     j=30: drain(29), vmcnt(16) = group 31 done.  j=31: drain(30), bar.
//     post: drain(31). Peak in flight 48 < 63. Raw s_barrier + counted
//     vmcnt (never __syncthreads - would drain the pipeline).

constexpr int T_LEN = 1024;
constexpr int TB    = 8;
constexpr int NBLK  = T_LEN / TB;   // 128
constexpr int BATCH = 32;
constexpr int NOUT  = 1024;
constexpr int BN    = BATCH * NOUT; // 32768 chains
constexpr int G     = 4;            // blocks per barrier iteration
constexpr int NITER = NBLK / G;     // 32
constexpr int RING  = 16;           // input tile ring (4 groups of G)
constexpr int CPW   = 128;          // chains per WG
constexpr int TILE  = TB * CPW;     // 1024 floats = 4KB

typedef float f4 __attribute__((ext_vector_type(4)));

__device__ __forceinline__ void dma16(const float* g, float* l) {
    __builtin_amdgcn_global_load_lds(
        (const __attribute__((address_space(1))) void*)g,
        (__attribute__((address_space(3))) void*)l, 16, 0, 0);
}

__global__ __launch_bounds__(128, 1)
void snn_blocks_kernel(const float* __restrict__ x,
                       const float* __restrict__ beta_raw,
                       const float* __restrict__ p_raw,
                       const float* __restrict__ b_raw,
                       float* __restrict__ out)
{
    __shared__ float inbuf[RING][TILE];   // 64KB DMA-written input ring
    __shared__ float sbuf[2][G][TILE];    // 32KB ping-pong spike staging

    const int tid  = threadIdx.x;
    const int lane = tid & 63;
    const int wid  = tid >> 6;              // 0 = consumer, 1 = producer
    const int wg0  = blockIdx.x * CPW;      // flat chain offset of this WG

    if (wid == 1) {
        // ================= PRODUCER WAVE (all vmem) =================
        const int rowsel = lane >> 5;              // 0 or 1
        const int col4   = (lane & 31) * 4;        // 0..124
        const float* xb = x   + wg0 + col4;
        float*       ob = out + wg0 + col4;

        auto dmaGroup = [&](int j2) {      // DMA the G tiles of iter j2
#pragma unroll
            for (int i = 0; i < G; ++i) {
                const int b = j2 * G + i;
                float* tile = &inbuf[b & (RING - 1)][0];
#pragma unroll
                for (int s = 0; s < 4; ++s) {
                    const float* g =
                        xb + (ptrdiff_t)(b * TB + 2 * s + rowsel) * BN;
                    dma16(g, tile + s * 256);
                }
            }
        };
        auto drainIter = [&](int j) {      // store spikes staged at iter j
#pragma unroll
            for (int i = 0; i < G; ++i) {
                const int b = j * G + i;
                const float* sf = &sbuf[j & 1][i][0];
#pragma unroll
                for (int s = 0; s < 4; ++s) {
                    f4 v = *(const f4*)(sf + s * 256 + lane * 4);
                    *(f4*)(ob + (ptrdiff_t)(b * TB + 2 * s + rowsel) * BN)
                        = v;
                }
            }
        };

        // prologue: groups 0 and 1 (blocks 0..7)
        dmaGroup(0);
        dmaGroup(1);
        asm volatile("s_waitcnt vmcnt(16)" ::: "memory");  // group 0 done
        __builtin_amdgcn_s_barrier();
        asm volatile("" ::: "memory");

        // j = 0: no drain yet
        dmaGroup(2);
        asm volatile("s_waitcnt vmcnt(16)" ::: "memory");  // group 1 done
        __builtin_amdgcn_s_barrier();
        asm volatile("" ::: "memory");

        // j = 1..29: steady state
#pragma unroll 1
        for (int j = 1; j <= 29; ++j) {
            drainIter(j - 1);
            dmaGroup(j + 2);
            asm volatile("s_waitcnt vmcnt(16)" ::: "memory"); // group j+1
            __builtin_amdgcn_s_barrier();
            asm volatile("" ::: "memory");
        }

        // j = 30: ring fully issued (group 31 = blocks 124..127)
        drainIter(29);
        asm volatile("s_waitcnt vmcnt(16)" ::: "memory");  // group 31 done
        __builtin_amdgcn_s_barrier();
        asm volatile("" ::: "memory");

        // j = 31
        drainIter(30);
        __builtin_amdgcn_s_barrier();
        asm volatile("" ::: "memory");

        // post-loop: spikes of iter 31 (blocks 124..127); visible via
        // consumer's lgkmcnt(0) before its final barrier.
        drainIter(31);
    } else {
        // ============ CONSUMER WAVE (zero vmem, 2 chains/lane) ============
        double pC[2], pp2C[2], pp4C[2], pp8C[2], invpC[2], betaC[2];
        double bbpC[2][8];
#pragma unroll
        for (int c = 0; c < 2; ++c) {
            const int n = (wg0 + c * 64 + lane) & (NOUT - 1);
            double beta = (double)beta_raw[n];
            beta = beta < 0.001 ? 0.001 : (beta > 0.999 ? 0.999 : beta);
            double p = fabs((double)p_raw[n]);
            p = p > 0.999 ? 0.999 : p;
            double bb = fabs((double)b_raw[n]);
            bb = bb < 0.001 ? 0.001 : (bb > 1.0 ? 1.0 : bb);
            double ppow[9];
            ppow[0] = 1.0;
#pragma unroll
            for (int i = 1; i <= 8; ++i) ppow[i] = ppow[i - 1] * p;
#pragma unroll
            for (int t = 0; t < 8; ++t) bbpC[c][t] = bb * ppow[t + 1];
            betaC[c] = beta;   pC[c]   = p;
            pp2C[c]  = ppow[2]; pp4C[c] = ppow[4]; pp8C[c] = ppow[8];
            invpC[c] = 1.0 / p;
        }

        double m[2]  = {0.0, 0.0};
        double a[2]  = {0.0, 0.0};
        int maskf[2]  = {0, 0};
        int firstp[2] = {0, 0};

        __builtin_amdgcn_s_barrier();       // matches producer prologue
        asm volatile("" ::: "memory");

#pragma unroll 1
        for (int j = 0; j < NITER; ++j) {
            const int g0 = (j & 3) * G;     // base tile slot of this group

#pragma unroll
            for (int i = 0; i < G; ++i) {
                const float* tile = &inbuf[g0 + i][0];
                float cur[2][8];
#pragma unroll
                for (int c = 0; c < 2; ++c)
#pragma unroll
                    for (int t = 0; t < 8; ++t)
                        cur[c][t] = tile[t * CPW + c * 64 + lane];

                // two independent chains; scheduler interleaves their ops
#pragma unroll
                for (int c = 0; c < 2; ++c) {
                    // ---- header: adaptation from prev-block stats ----
                    double pf1 = pC[c];                 // -> p^(firstp+1)
                    pf1 *= (firstp[c] & 1) ? pC[c]   : 1.0;
                    pf1 *= (firstp[c] & 2) ? pp2C[c] : 1.0;
                    pf1 *= (firstp[c] & 4) ? pp4C[c] : 1.0;
                    const int dsteps = firstp[c] ^ 7;   // 7 - firstp
                    double pd = (dsteps & 1) ? pC[c] : 1.0;
                    pd *= (dsteps & 2) ? pp2C[c] : 1.0;
                    pd *= (dsteps & 4) ? pp4C[c] : 1.0;
                    const double new_a = (a[c] * pf1 + invpC[c]) * pd;
                    double vinit;
                    if (maskf[c]) { a[c] = new_a;          vinit = 0.0;  }
                    else          { a[c] = pp8C[c] * a[c]; vinit = m[c]; }

                    // refractory mask: prev z[t]==0 <=> t < firstp
                    const int zmask = maskf[c] ? ((1 << firstp[c]) - 1) : 0;

                    int fbits = 0;
                    double mm = vinit;
#pragma unroll
                    for (int t = 0; t < 8; ++t) {
                        const float xf =
                            ((zmask >> t) & 1) ? 0.0f : cur[c][t];
                        mm = betaC[c] * mm + (double)xf;   // causal decay
                        const double vth = 1.0 + bbpC[c][t] * a[c];
                        fbits |= (mm - vth > 0.0) ? (1 << t) : 0;
                    }
                    m[c] = mm;
                    maskf[c]  = (fbits != 0);
                    firstp[c] = fbits ? __builtin_ctz(fbits) : 0;

                    // stage spikes (one-hot at firstp) for producer drain
#pragma unroll
                    for (int t = 0; t < 8; ++t)
                        sbuf[j & 1][i][t * CPW + c * 64 + lane] =
                            (maskf[c] && t == firstp[c]) ? 1.0f : 0.0f;
                }
            }

            asm volatile("s_waitcnt lgkmcnt(0)" ::: "memory");
            __builtin_amdgcn_s_barrier();
            asm volatile("" ::: "memory");
        }
    }
}

extern "C" void kernel_launch(void* const* d_in, const int* in_sizes, int n_in,
                              void* d_out, int out_size, void* d_ws, size_t ws_size,
                              hipStream_t stream) {
    const float* x        = (const float*)d_in[0];
    const float* beta_raw = (const float*)d_in[1];
    const float* p_raw    = (const float*)d_in[2];
    const float* b_raw    = (const float*)d_in[3];
    float* out            = (float*)d_out;

    dim3 grid(BN / CPW);   // 256 WGs x (1 consumer + 1 producer) wave
    dim3 block(128);
    snn_blocks_kernel<<<grid, block, 0, stream>>>(x, beta_raw, p_raw, b_raw, out);
}

// Round 7
// 241.724 us; speedup vs baseline: 1.1123x; 1.1123x over previous
//
#include <hip/hip_runtime.h>

// Blocks SNN forward: T=1024, TB=8, B=32, N=1024.
// R14: consumer = pure math + direct coalesced stores; producer = DMA-only.
//
// Evidence chain: R7/R9/R11/R12 all ~85us (~1600cy/block/chain); R13
// (ILP-2) showed per-chain cost with latency hidden ~1050cy but regressed
// wall time (wall = per-wave serial time; never lengthen it). The ~550cy
// gap between 1600 and 1050 is per-block EXPOSED latency: per-block cur
// ds_reads (+lgkm), sbuf staging ds_writes, and the producer's
// sbuf-read->store->vmcnt drain leaking through the barrier. R14 removes
// all of it from the per-block path:
//   * G=8 blocks per iteration; all 64 cur ds_reads hoisted to group top,
//     ONE lgkmcnt(0) per 8 blocks (~15cy/block amortized).
//   * NO sbuf: consumer stores spikes directly, 8 scalar dword stores per
//     block (64 lanes x 4B = 256B contiguous = perfectly coalesced),
//     fire-and-forget (no waits ever follow them; plain stores ack at L2
//     per R9 lesson). Producer never touches stores -> its vmcnt ledger
//     counts only DMAs.
//   * Producer DMA-only: 16-op groups, steady vmcnt(16), exact
//     prologue/tail; 17 barriers each side; RING=4 groups (64KB) makes
//     slot reuse race-free (group j+2 written at iter j reuses slots the
//     consumer finished at barrier j-1).
// Math verbatim from R8-R13 (absmax 0.0 proven): first-spike closed form,
// f64 Horner membrane, exact op order preserved.
// Decision rule: if this lands >=80us, ~1600cy/block is intrinsic f64
// issue+dep cost of the serial recurrence at 1 wave/SIMD -> roofline.

constexpr int T_LEN = 1024;
constexpr int TB    = 8;
constexpr int NBLK  = T_LEN / TB;   // 128
constexpr int BATCH = 32;
constexpr int NOUT  = 1024;
constexpr int BN    = BATCH * NOUT; // 32768 chains
constexpr int G     = 8;            // blocks per barrier iteration
constexpr int NITER = NBLK / G;     // 16
constexpr int RING  = 32;           // input tile ring (4 groups of G)

__device__ __forceinline__ void dma16(const float* g, float* l) {
    __builtin_amdgcn_global_load_lds(
        (const __attribute__((address_space(1))) void*)g,
        (__attribute__((address_space(3))) void*)l, 16, 0, 0);
}

__global__ __launch_bounds__(128, 1)
void snn_blocks_kernel(const float* __restrict__ x,
                       const float* __restrict__ beta_raw,
                       const float* __restrict__ p_raw,
                       const float* __restrict__ b_raw,
                       float* __restrict__ out)
{
    __shared__ float inbuf[RING][TB * 64];   // 64KB DMA-written input ring

    const int tid  = threadIdx.x;
    const int lane = tid & 63;
    const int wid  = tid >> 6;              // 0 = consumer, 1 = producer
    const int wg0  = blockIdx.x * 64;       // flat chain offset of this WG

    if (wid == 1) {
        // ================= PRODUCER WAVE (DMA-only) =================
        // lane p writes LDS bytes [16p,16p+16) of each 2KB tile == rows
        // (p>>4) [+4 for 2nd op], cols (p&15)*4..+3 (R10/R11-proven).
        const int rowoff = lane >> 4;
        const int coloff = wg0 + (lane & 15) * 4;
        const float* xbase = x + (ptrdiff_t)rowoff * BN + coloff;

        auto dmaGroup = [&](int jg) {       // 16 DMA ops = blocks of iter jg
#pragma unroll
            for (int i = 0; i < G; ++i) {
                const int b = jg * G + i;
                float* tile = &inbuf[(jg & 3) * G + i][0];
                const float* g = xbase + (ptrdiff_t)(b * TB) * BN;
                dma16(g,          tile);
                dma16(g + 4 * BN, tile + 256);
            }
        };

        // prologue: groups 0,1 issued (32 ops); vmcnt(16) = group 0 done
        dmaGroup(0);
        dmaGroup(1);
        asm volatile("s_waitcnt vmcnt(16)" ::: "memory");
        __builtin_amdgcn_s_barrier();                     // barrier #0
        asm volatile("" ::: "memory");

        // j = 0..13: issue group j+2, guarantee group j+1 done
#pragma unroll 1
        for (int j = 0; j <= 13; ++j) {
            dmaGroup(j + 2);
            asm volatile("s_waitcnt vmcnt(16)" ::: "memory");
            __builtin_amdgcn_s_barrier();                 // barrier #j+1
            asm volatile("" ::: "memory");
        }
        // j = 14: guarantee group 15 done
        asm volatile("s_waitcnt vmcnt(0)" ::: "memory");
        __builtin_amdgcn_s_barrier();                     // barrier #15
        asm volatile("" ::: "memory");
        // j = 15: consumer computing group 15
        __builtin_amdgcn_s_barrier();                     // barrier #16
    } else {
        // ========== CONSUMER WAVE (pure math + direct stores) ==========
        const int gid = wg0 + lane;         // = b*NOUT + n
        const int n   = gid & (NOUT - 1);
        float* ob = out + gid;

        // clamped properties (f64)
        double beta = (double)beta_raw[n];
        beta = beta < 0.001 ? 0.001 : (beta > 0.999 ? 0.999 : beta);
        double p = fabs((double)p_raw[n]);
        p = p > 0.999 ? 0.999 : p;
        double bb = fabs((double)b_raw[n]);
        bb = bb < 0.001 ? 0.001 : (bb > 1.0 ? 1.0 : bb);
        const double inv_p = 1.0 / p;

        double ppow[9];
        ppow[0] = 1.0;
#pragma unroll
        for (int i = 1; i <= 8; ++i) ppow[i] = ppow[i - 1] * p;
        double bbp[8];
#pragma unroll
        for (int t = 0; t < 8; ++t) bbp[t] = bb * ppow[t + 1];
        const double pp2 = ppow[2], pp4 = ppow[4], pp8 = ppow[8];

        double m = 0.0, a = 0.0;
        int maskf = 0, firstp = 0;

        __builtin_amdgcn_s_barrier();       // barrier #0 (group 0 ready)
        asm volatile("" ::: "memory");

#pragma unroll 1
        for (int j = 0; j < NITER; ++j) {
            const int s0 = (j & 3) * G;     // base tile slot of this group

            // hoist ALL group reads; one lgkm wait per 8 blocks
            float cur[G][8];
#pragma unroll
            for (int i = 0; i < G; ++i)
#pragma unroll
                for (int t = 0; t < 8; ++t)
                    cur[i][t] = inbuf[s0 + i][t * 64 + lane];
            asm volatile("s_waitcnt lgkmcnt(0)" ::: "memory");

#pragma unroll
            for (int i = 0; i < G; ++i) {
                const int blk = j * G + i;

                // ---- header: adaptation update from prev-block stats ----
                double pf1 = p;                        // -> p^(firstp+1)
                pf1 *= (firstp & 1) ? p   : 1.0;
                pf1 *= (firstp & 2) ? pp2 : 1.0;
                pf1 *= (firstp & 4) ? pp4 : 1.0;
                const int dsteps = firstp ^ 7;         // 7 - firstp
                double pd = (dsteps & 1) ? p : 1.0;
                pd *= (dsteps & 2) ? pp2 : 1.0;
                pd *= (dsteps & 4) ? pp4 : 1.0;
                const double new_a = (a * pf1 + inv_p) * pd;
                double vinit;
                if (maskf) { a = new_a;   vinit = 0.0; }  // v_init = 0
                else       { a = pp8 * a; vinit = m;   }  // keep int_mem

                // refractory mask: prev z[t]==0 <=> t < firstp (if maskf)
                const int zmask = maskf ? ((1 << firstp) - 1) : 0;

                int fbits = 0;
                double mm = vinit;
#pragma unroll
                for (int t = 0; t < 8; ++t) {
                    const float xf = ((zmask >> t) & 1) ? 0.0f : cur[i][t];
                    mm = beta * mm + (double)xf;          // causal decay sum
                    const double vth = 1.0 + bbp[t] * a;  // 1+bb*p^(t+1)*a
                    fbits |= (mm - vth > 0.0) ? (1 << t) : 0; // heaviside
                }
                m = mm;
                maskf  = (fbits != 0);
                firstp = fbits ? __builtin_ctz(fbits) : 0;

                // direct coalesced spike stores (one-hot at firstp);
                // fire-and-forget: nothing in this wave ever waits on them.
#pragma unroll
                for (int t = 0; t < 8; ++t) {
                    const float sv = (maskf && t == firstp) ? 1.0f : 0.0f;
                    ob[(ptrdiff_t)(blk * TB + t) * BN] = sv;
                }
            }

            __builtin_amdgcn_s_barrier();   // barrier #j+1 (group consumed)
            asm volatile("" ::: "memory");
        }
    }
}

extern "C" void kernel_launch(void* const* d_in, const int* in_sizes, int n_in,
                              void* d_out, int out_size, void* d_ws, size_t ws_size,
                              hipStream_t stream) {
    const float* x        = (const float*)d_in[0];
    const float* beta_raw = (const float*)d_in[1];
    const float* p_raw    = (const float*)d_in[2];
    const float* b_raw    = (const float*)d_in[3];
    float* out            = (float*)d_out;

    dim3 grid(BN / 64);   // 512 WGs x (1 consumer + 1 producer) wave
    dim3 block(128);
    snn_blocks_kernel<<<grid, block, 0, stream>>>(x, beta_raw, p_raw, b_raw, out);
}

// Round 8
// 237.705 us; speedup vs baseline: 1.1311x; 1.0169x over previous
//
#include <hip/hip_runtime.h>

// Blocks SNN forward: T=1024, TB=8, B=32, N=1024.
// R15: time-relay across 8 waves. Wave w of a WG computes blocks
// k === w (mod 8) of the SAME 64-chain stripe; the carry state
// (m, a, maskf, firstp) hops wave-to-wave through LDS with a
// generation-tagged flag + spin-wait.
//
// Why: R7-R14 varied every element of the single-wave schedule (register
// prefetch, DMA ring, producer/consumer, barrier granularity, ILP-2,
// pure-math consumer) and the per-wave floor stayed ~1600cy/block
// (~300cy issue + ~1300cy stall). Wall = per-wave serial time at 1
// wave/SIMD, so the only remaining lever is removing EVERYTHING except
// the carry math from the serial wave: relay waves keep only
// {spin-detect ~140 + carry-read ~120 (overlapped with the firstp-only
// header chain) + math ~300 + carry-write ~150} on the critical path.
// All per-wave overhead (x DMA, vmcnt waits, spike stores) lands in each
// wave's 7 idle slots (~4000cy slack) where stalls are free; per-wave
// vmem rate drops 8x.
//
// Sync protocol (race-free, no speculation):
//   writer (block k): ds_write m,a -> s_waitcnt lgkmcnt(0) ->
//                     ds_write pk = ((k+1)<<8)|maskf<<4|firstp
//   reader (block k+1): spin on volatile pk until gen==k+1; memory
//                       clobber; then plain ds_read m,a (strictly after).
//   Ring=16 slots, generation check kills ABA; zero-init via one
//   __syncthreads (which also drains the prologue DMA).
// vmcnt ledger per wave per round: [DMA pair (k+8)] then [8 spike
// stores]; at next round top vmcnt(8) => the DMA pair (oldest) retired.
// asm memory clobbers pin the DMA-before-stores issue order.
// Math verbatim from R8-R14 (absmax 0.0 proven).
//
// Occupancy: 512 WGs x 512 thr = 4096 waves = 4/SIMD; LDS 52KB -> 2
// WGs/CU; __launch_bounds__(512,4) caps VGPR at 128 (est ~90).

constexpr int T_LEN = 1024;
constexpr int TB    = 8;
constexpr int NBLK  = T_LEN / TB;   // 128
constexpr int BATCH = 32;
constexpr int NOUT  = 1024;
constexpr int BN    = BATCH * NOUT; // 32768 chains
constexpr int W     = 8;            // relay waves per WG
constexpr int NRND  = NBLK / W;     // 16 rounds per wave
constexpr int RING  = 16;           // carry ring slots

__device__ __forceinline__ void dma16(const float* g, float* l) {
    __builtin_amdgcn_global_load_lds(
        (const __attribute__((address_space(1))) void*)g,
        (__attribute__((address_space(3))) void*)l, 16, 0, 0);
}

__global__ __launch_bounds__(512, 4)
void snn_blocks_kernel(const float* __restrict__ x,
                       const float* __restrict__ beta_raw,
                       const float* __restrict__ p_raw,
                       const float* __restrict__ b_raw,
                       float* __restrict__ out)
{
    __shared__ float    stg[W][2][TB * 64];     // 32KB per-wave dbuf staging
    __shared__ double   carry_ma[RING][2 * 64]; // 16KB: m,a per lane
    __shared__ unsigned carry_pk[RING][64];     // 4KB: gen|maskf|firstp

    const int tid  = threadIdx.x;
    const int lane = tid & 63;
    const int w    = tid >> 6;              // relay wave id 0..7
    const int wg0  = blockIdx.x * 64;       // 64-chain stripe offset
    const int gid  = wg0 + lane;            // = b*NOUT + n
    const int n    = gid & (NOUT - 1);

    // clamped properties (f64) — identical for all 8 waves of the WG
    double beta = (double)beta_raw[n];
    beta = beta < 0.001 ? 0.001 : (beta > 0.999 ? 0.999 : beta);
    double p = fabs((double)p_raw[n]);
    p = p > 0.999 ? 0.999 : p;
    double bb = fabs((double)b_raw[n]);
    bb = bb < 0.001 ? 0.001 : (bb > 1.0 ? 1.0 : bb);
    const double inv_p = 1.0 / p;

    double ppow[9];
    ppow[0] = 1.0;
#pragma unroll
    for (int i = 1; i <= 8; ++i) ppow[i] = ppow[i - 1] * p;
    double bbp[8];
#pragma unroll
    for (int t = 0; t < 8; ++t) bbp[t] = bb * ppow[t + 1];
    const double pp2 = ppow[2], pp4 = ppow[4], pp8 = ppow[8];

    // zero the generation words (1024 words, 512 threads -> 2 each)
    {
        unsigned* pkflat = &carry_pk[0][0];
        pkflat[tid]       = 0u;
        pkflat[tid + 512] = 0u;
    }

    // prologue: each wave DMAs its first block (block w) into stg[w][0].
    // DMA HW layout: lane p writes LDS bytes [16p,16p+16) == rows (p>>4)
    // [+4 for op 2], cols (p&15)*4..+3 (R10/R11-proven).
    const float* xb_dma = x + (ptrdiff_t)(lane >> 4) * BN + wg0 + (lane & 15) * 4;
    {
        const float* g = xb_dma + (ptrdiff_t)(w * TB) * BN;
        dma16(g,          &stg[w][0][0]);
        dma16(g + 4 * BN, &stg[w][0][256]);
    }
    __syncthreads();   // drains each wave's DMA (vmcnt 0) + flags visible

    float* ob = out + gid;

#pragma unroll 1
    for (int r = 0; r < NRND; ++r) {
        const int k = r * W + w;            // this wave's block

        // my DMA for block k (issued last round; round 0 covered by
        // __syncthreads). 8 spike stores issued after it -> vmcnt(8).
        if (r > 0)
            asm volatile("s_waitcnt vmcnt(8)" ::: "memory");

        // pre-read x into regs (lgkm drains during the spin below)
        float cur[8];
#pragma unroll
        for (int t = 0; t < 8; ++t)
            cur[t] = stg[w][r & 1][t * 64 + lane];

        // ---- acquire carry for block k ----
        double m, a;
        int maskf, firstp;
        if (k == 0) {
            m = 0.0; a = 0.0; maskf = 0; firstp = 0;
        } else {
            const int slot = k & (RING - 1);
            volatile unsigned* vpk = (volatile unsigned*)&carry_pk[slot][lane];
            unsigned pk;
            do { pk = *vpk; } while ((pk >> 8) != (unsigned)k);
            asm volatile("" ::: "memory");  // no hoisting of m,a above spin
            maskf  = (pk >> 4) & 1;
            firstp = pk & 7;
            m = carry_ma[slot][2 * lane];       // plain reads, strictly
            a = carry_ma[slot][2 * lane + 1];   // after detect
        }

        __builtin_amdgcn_s_setprio(1);

        // ---- header: adaptation update from prev-block stats ----
        double pf1 = p;                        // -> p^(firstp+1)
        pf1 *= (firstp & 1) ? p   : 1.0;
        pf1 *= (firstp & 2) ? pp2 : 1.0;
        pf1 *= (firstp & 4) ? pp4 : 1.0;
        const int dsteps = firstp ^ 7;         // 7 - firstp
        double pd = (dsteps & 1) ? p : 1.0;
        pd *= (dsteps & 2) ? pp2 : 1.0;
        pd *= (dsteps & 4) ? pp4 : 1.0;
        const double new_a = (a * pf1 + inv_p) * pd;
        double vinit;
        if (maskf) { a = new_a;   vinit = 0.0; }  // v_init = 0
        else       { a = pp8 * a; vinit = m;   }  // keep int_mem

        // refractory mask: prev z[t]==0 <=> t < firstp (when maskf)
        const int zmask = maskf ? ((1 << firstp) - 1) : 0;

        int fbits = 0;
        double mm = vinit;
#pragma unroll
        for (int t = 0; t < 8; ++t) {
            const float xf = ((zmask >> t) & 1) ? 0.0f : cur[t];
            mm = beta * mm + (double)xf;           // causal decayed sum
            const double vth = 1.0 + bbp[t] * a;   // 1 + bb*p^(t+1)*a
            fbits |= (mm - vth > 0.0) ? (1 << t) : 0;  // heaviside
        }
        const int nmaskf  = (fbits != 0) ? 1 : 0;
        const int nfirstp = fbits ? __builtin_ctz(fbits) : 0;

        // ---- hand off carry for block k+1 ----
        {
            const int s2 = (k + 1) & (RING - 1);
            carry_ma[s2][2 * lane]     = mm;
            carry_ma[s2][2 * lane + 1] = a;
            asm volatile("s_waitcnt lgkmcnt(0)" ::: "memory"); // data first
            carry_pk[s2][lane] =
                ((unsigned)(k + 1) << 8) | (nmaskf << 4) | nfirstp;
        }
        __builtin_amdgcn_s_setprio(0);
        asm volatile("" ::: "memory");

        // ---- idle-slot work (7 slots of slack) ----
        // prefetch DMA for block k+8 into the other staging half
        if (k + W < NBLK) {
            const float* g = xb_dma + (ptrdiff_t)((k + W) * TB) * BN;
            float* l = &stg[w][(r + 1) & 1][0];
            dma16(g,          l);
            dma16(g + 4 * BN, l + 256);
        }
        asm volatile("" ::: "memory");  // pin DMA-before-stores vmem order

        // spike stores of block k: one-hot at nfirstp, coalesced,
        // fire-and-forget (next round's vmcnt(8) tolerates them).
#pragma unroll
        for (int t = 0; t < 8; ++t) {
            const float sv = (nmaskf && t == nfirstp) ? 1.0f : 0.0f;
            ob[(ptrdiff_t)(k * TB + t) * BN] = sv;
        }
        asm volatile("" ::: "memory");
    }
}

extern "C" void kernel_launch(void* const* d_in, const int* in_sizes, int n_in,
                              void* d_out, int out_size, void* d_ws, size_t ws_size,
                              hipStream_t stream) {
    const float* x        = (const float*)d_in[0];
    const float* beta_raw = (const float*)d_in[1];
    const float* p_raw    = (const float*)d_in[2];
    const float* b_raw    = (const float*)d_in[3];
    float* out            = (float*)d_out;

    dim3 grid(BN / 64);   // 512 WGs x 8 relay waves
    dim3 block(512);
    snn_blocks_kernel<<<grid, block, 0, stream>>>(x, beta_raw, p_raw, b_raw, out);
}